// Round 5
// baseline (242.530 us; speedup 1.0000x reference)
//
#include <hip/hip_runtime.h>

// SpatialLinearAttention on MI355X — round 5: two-pass dataflow, no q intermediate.
// k_wconv  (Wqkv -> bf16)
// k_ctxp   (k,v GEMM + exp + per-block ctx/sumexp partials; reg-accumulated over 4 subtiles,
//           double-buffered x stage, 2 syncs/subtile)
// k_mbuild (reduce 16 partials/frame + M = Wout.blockdiag(ctx^T)*SCALE/n/sumexp -> bf16)
// k_fout   (q GEMM + in-reg softmax + in-reg shuffle B-frags + M@q_sm + bout; 1 sync)

constexpr float kSCALE = 0.17677669529663687f; // 32^-0.5

typedef __attribute__((ext_vector_type(8))) short short8;   // 8 bf16 (4 VGPRs)
typedef __attribute__((ext_vector_type(4))) float f32x4;    // MFMA acc

__device__ __forceinline__ float bfu2f(unsigned int u) {
  union { unsigned int i; float f; } c; c.i = u << 16; return c.f;
}
__device__ __forceinline__ unsigned short f2bf(float f) {
  union { float f; unsigned int i; } c; c.f = f;
  unsigned int r = c.i + 0x7fffu + ((c.i >> 16) & 1u);  // RNE
  return (unsigned short)(r >> 16);
}
__device__ __forceinline__ void pack8(const float* v, unsigned short* dst16) {
  union { unsigned short u[8]; uint4 q; } t;
  #pragma unroll
  for (int i = 0; i < 8; ++i) t.u[i] = f2bf(v[i]);
  *(uint4*)dst16 = t.q;
}

// ---------------------------------------------------------------- K0: W -> bf16
__global__ __launch_bounds__(256) void k_wconv(const float* __restrict__ W,
                                               unsigned short* __restrict__ Wbf) {
  const int i = (blockIdx.x * 256 + threadIdx.x) * 4;   // 49152 elems total
  const float4 v = *(const float4*)&W[i];
  union { unsigned short u[4]; uint2 q; } t;
  t.u[0] = f2bf(v.x); t.u[1] = f2bf(v.y); t.u[2] = f2bf(v.z); t.u[3] = f2bf(v.w);
  *(uint2*)&Wbf[i] = t.q;
}

// ---------------------------------------------------------------- K1: ctx partials
// grid (16 ntiles of 256 n, 32 frames), 512 thr (8 waves; wave GEMM tile 64o x 32n).
// 4 subtiles of 64 n; ctx + sumexp accumulate in registers across subtiles.
__global__ __launch_bounds__(512, 4) void k_ctxp(const float* __restrict__ x,
                                                 const unsigned short* __restrict__ Wbf,
                                                 float* __restrict__ ctxp,
                                                 float* __restrict__ sexp) {
  __shared__ __align__(16) unsigned short R0[2][64 * 128];  // x subtile [n][c^], dbuf
  __shared__ __align__(16) unsigned short EK[128 * 64];     // exp(k) [d][n^]
  __shared__ __align__(16) unsigned short VV[128 * 64];     // v      [e][n^]
  const int nt = blockIdx.x, fr = blockIdx.y;
  const int bb = fr >> 4, ff = fr & 15;
  const int tid = threadIdx.x;
  const float* xfr = x + ((size_t)bb * 2048 + ff) * 4096;   // [c][n], c-stride 65536 f32
  const int nbase = nt * 256;

  const int l = tid & 63, w = tid >> 6;
  const int wo = (w >> 1) * 64, wn = (w & 1) * 32;          // W row = 128 + wo + ...
  const int lr = l & 15, lg = l >> 4;
  const int nn = tid & 63, cg = tid >> 6;                   // stage mapping

  f32x4 c2[2][2];                                           // ctx accum (waves 0-3)
  c2[0][0] = 0.f; c2[0][1] = 0.f; c2[1][0] = 0.f; c2[1][1] = 0.f;
  float se = 0.f;                                           // sumexp accum (waves 4-7)

  float pre[16];
  #pragma unroll
  for (int p = 0; p < 2; ++p)
    #pragma unroll
    for (int j = 0; j < 8; ++j)
      pre[p * 8 + j] = xfr[(size_t)((cg * 2 + p) * 8 + j) * 65536 + nbase + nn];

  #pragma unroll
  for (int sub = 0; sub < 4; ++sub) {
    unsigned short* Rb = R0[sub & 1];
    // write prefetched x subtile into LDS
    pack8(pre + 0, &Rb[nn * 128 + ((cg * 16 + 0) ^ ((nn & 7) << 3))]);
    pack8(pre + 8, &Rb[nn * 128 + ((cg * 16 + 8) ^ ((nn & 7) << 3))]);
    __syncthreads();   // A: stage visible; prev-iter EK/VV readers done
    if (sub < 3) {     // prefetch next subtile (in flight during GEMM)
      #pragma unroll
      for (int p = 0; p < 2; ++p)
        #pragma unroll
        for (int j = 0; j < 8; ++j)
          pre[p * 8 + j] = xfr[(size_t)((cg * 2 + p) * 8 + j) * 65536 + nbase + (sub + 1) * 64 + nn];
    }
    // GEMM k,v: 256 x 64 tile
    f32x4 acc[4][2];
    #pragma unroll
    for (int i = 0; i < 4; ++i) { acc[i][0] = 0.f; acc[i][1] = 0.f; }
    #pragma unroll
    for (int ks = 0; ks < 4; ++ks) {
      const int k0 = ks * 32 + lg * 8;
      short8 a[4], b[2];
      #pragma unroll
      for (int i = 0; i < 4; ++i)
        a[i] = *(const short8*)&Wbf[(size_t)(128 + wo + 16 * i + lr) * 128 + k0];
      #pragma unroll
      for (int j = 0; j < 2; ++j) {
        const int n = wn + 16 * j + lr;
        b[j] = *(const short8*)&Rb[n * 128 + (k0 ^ ((n & 7) << 3))];
      }
      #pragma unroll
      for (int i = 0; i < 4; ++i)
        #pragma unroll
        for (int j = 0; j < 2; ++j)
          acc[i][j] = __builtin_amdgcn_mfma_f32_16x16x32_bf16(a[i], b[j], acc[i][j], 0, 0, 0);
    }
    // k -> exp -> EK ; v -> VV
    if (wo < 128) {
      #pragma unroll
      for (int i = 0; i < 4; ++i)
        #pragma unroll
        for (int j = 0; j < 2; ++j) {
          const int n = wn + 16 * j + lr;
          #pragma unroll
          for (int r = 0; r < 4; ++r) {
            const int dd = wo + 16 * i + 4 * lg + r;
            EK[dd * 64 + (n ^ ((dd & 7) << 3))] = f2bf(__expf(acc[i][j][r]));
          }
        }
    } else {
      #pragma unroll
      for (int i = 0; i < 4; ++i)
        #pragma unroll
        for (int j = 0; j < 2; ++j) {
          const int n = wn + 16 * j + lr;
          #pragma unroll
          for (int r = 0; r < 4; ++r) {
            const int e = wo - 128 + 16 * i + 4 * lg + r;
            VV[e * 64 + (n ^ ((e & 7) << 3))] = f2bf(acc[i][j][r]);
          }
        }
    }
    __syncthreads();   // B: EK/VV visible; R0[sub&1] GEMM reads done
    if (w < 4) {
      const int h = w;
      #pragma unroll
      for (int ks2 = 0; ks2 < 2; ++ks2) {
        const int k0 = ks2 * 32 + lg * 8;
        short8 a2[2], b2[2];
        #pragma unroll
        for (int i2 = 0; i2 < 2; ++i2) {
          const int row = h * 32 + 16 * i2 + lr;
          a2[i2] = *(const short8*)&EK[row * 64 + (k0 ^ ((row & 7) << 3))];
          b2[i2] = *(const short8*)&VV[row * 64 + (k0 ^ ((row & 7) << 3))];
        }
        #pragma unroll
        for (int i2 = 0; i2 < 2; ++i2)
          #pragma unroll
          for (int j2 = 0; j2 < 2; ++j2)
            c2[i2][j2] = __builtin_amdgcn_mfma_f32_16x16x32_bf16(a2[i2], b2[j2], c2[i2][j2], 0, 0, 0);
      }
    } else {
      const int h = w - 4;
      const int rl = l & 31, half = l >> 5;
      const int row = h * 32 + rl;
      #pragma unroll
      for (int m = 0; m < 4; ++m) {
        const int ng = (half * 32 + m * 8) ^ ((row & 7) << 3);
        const uint4 u = *(const uint4*)&EK[row * 64 + ng];
        se += bfu2f(u.x & 0xffffu) + bfu2f(u.x >> 16) + bfu2f(u.y & 0xffffu) + bfu2f(u.y >> 16)
            + bfu2f(u.z & 0xffffu) + bfu2f(u.z >> 16) + bfu2f(u.w & 0xffffu) + bfu2f(u.w >> 16);
      }
    }
  }
  // epilogue: store reg-accumulated partials
  const int bp = fr * 16 + nt;
  if (w < 4) {
    float* cp = ctxp + ((size_t)bp * 4 + w) * 1024;
    #pragma unroll
    for (int i2 = 0; i2 < 2; ++i2)
      #pragma unroll
      for (int j2 = 0; j2 < 2; ++j2)
        #pragma unroll
        for (int r = 0; r < 4; ++r)
          cp[(16 * i2 + 4 * lg + r) * 32 + 16 * j2 + lr] = c2[i2][j2][r];
  } else {
    const int h = w - 4;
    const int rl = l & 31, half = l >> 5;
    se += __shfl_xor(se, 32);
    if (half == 0) sexp[(size_t)bp * 128 + h * 32 + rl] = se;
  }
}

// -------------------------------------------- K2: reduce partials + build M (bf16)
// grid (4 heads, 32 frames), 256 thr.
__global__ __launch_bounds__(256) void k_mbuild(const float* __restrict__ Wout,
                                                const float* __restrict__ ctxp,
                                                const float* __restrict__ sexp,
                                                unsigned short* __restrict__ Mbf) {
  __shared__ float Wo[128][33];   // Wout[o][h*32+e]
  __shared__ float cn[32][36];    // normalized ctx [d][e]
  __shared__ float ses[32];
  const int h = blockIdx.x, fr = blockIdx.y, tid = threadIdx.x;

  float4 c4 = make_float4(0.f, 0.f, 0.f, 0.f);
  {
    const float* base = ctxp + ((size_t)(fr * 16) * 4 + h) * 1024 + tid * 4;
    #pragma unroll
    for (int p = 0; p < 16; ++p) {
      const float4 v = *(const float4*)&base[(size_t)p * 4096];
      c4.x += v.x; c4.y += v.y; c4.z += v.z; c4.w += v.w;
    }
  }
  if (tid < 32) {
    float s = 0.f;
    const float* sb = sexp + (size_t)(fr * 16) * 128 + h * 32 + tid;
    #pragma unroll
    for (int p = 0; p < 16; ++p) s += sb[(size_t)p * 128];
    ses[tid] = s;
  }
  {
    const int o = tid >> 1, e0 = (tid & 1) * 16;
    #pragma unroll
    for (int q = 0; q < 4; ++q) {
      const float4 v = *(const float4*)&Wout[o * 128 + h * 32 + e0 + 4 * q];
      Wo[o][e0 + 4 * q] = v.x; Wo[o][e0 + 4 * q + 1] = v.y;
      Wo[o][e0 + 4 * q + 2] = v.z; Wo[o][e0 + 4 * q + 3] = v.w;
    }
  }
  __syncthreads();
  {
    const int dd = tid >> 3, e0 = (tid & 7) * 4;
    const float sc = kSCALE / (4096.f * ses[dd]);
    cn[dd][e0] = c4.x * sc; cn[dd][e0 + 1] = c4.y * sc;
    cn[dd][e0 + 2] = c4.z * sc; cn[dd][e0 + 3] = c4.w * sc;
  }
  __syncthreads();
  {
    const int o = tid >> 1, dbase = (tid & 1) * 16;
    union { unsigned short u[16]; uint4 q[2]; } t;
    #pragma unroll
    for (int dq = 0; dq < 16; ++dq) {
      const int dc = dbase + dq;
      float s = 0.f;
      #pragma unroll
      for (int e = 0; e < 32; ++e) s = fmaf(Wo[o][e], cn[dc][e], s);
      t.u[dq] = f2bf(s);
    }
    unsigned short* mb = Mbf + (size_t)fr * 16384 + o * 128 + h * 32 + dbase;
    *(uint4*)&mb[0] = t.q[0];
    *(uint4*)&mb[8] = t.q[1];
  }
}

// ---------------------------------------------------------------- K3: fused output
// grid (32 ntiles, 32 frames), 256 thr (4 waves; wave tile 128o x 32n).
// q GEMM -> in-reg softmax -> shuffle B-frags -> M @ q_sm -> + bout -> direct stores.
__global__ __launch_bounds__(256, 3) void k_fout(const float* __restrict__ x,
                                                 const unsigned short* __restrict__ Wbf,
                                                 const unsigned short* __restrict__ Mbf,
                                                 const float* __restrict__ bout,
                                                 float* __restrict__ out) {
  __shared__ __align__(16) unsigned short R0[128 * 128];   // x tile [n][c^]
  const int ntile = blockIdx.x, fr = blockIdx.y;
  const int bb = fr >> 4, ff = fr & 15;
  const int tid = threadIdx.x;
  const float* xfr = x + ((size_t)bb * 2048 + ff) * 4096;

  // ---- stage x: [128 n][128 c] bf16
  {
    const int nn = tid & 127, cg = tid >> 7;
    const int ng = ntile * 128 + nn;
    #pragma unroll
    for (int p = 0; p < 8; ++p) {
      const int c8 = cg * 8 + p;
      float v[8];
      #pragma unroll
      for (int j = 0; j < 8; ++j) v[j] = xfr[(size_t)(c8 * 8 + j) * 65536 + ng];
      pack8(v, &R0[nn * 128 + ((c8 * 8) ^ ((nn & 7) << 3))]);
    }
  }
  __syncthreads();

  const int l = tid & 63, w = tid >> 6;
  const int wn = w * 32;
  const int lr = l & 15, lg = l >> 4;

  // ---- GEMM1: q = Wq @ x, wave tile 128 x 32
  f32x4 acc[8][2];
  #pragma unroll
  for (int i = 0; i < 8; ++i) { acc[i][0] = 0.f; acc[i][1] = 0.f; }
  #pragma unroll
  for (int ks = 0; ks < 4; ++ks) {
    const int k0 = ks * 32 + lg * 8;
    short8 a[8], b[2];
    #pragma unroll
    for (int i = 0; i < 8; ++i) a[i] = *(const short8*)&Wbf[(size_t)(16 * i + lr) * 128 + k0];
    #pragma unroll
    for (int j = 0; j < 2; ++j) {
      const int n = wn + 16 * j + lr;
      b[j] = *(const short8*)&R0[n * 128 + (k0 ^ ((n & 7) << 3))];
    }
    #pragma unroll
    for (int i = 0; i < 8; ++i)
      #pragma unroll
      for (int j = 0; j < 2; ++j)
        acc[i][j] = __builtin_amdgcn_mfma_f32_16x16x32_bf16(a[i], b[j], acc[i][j], 0, 0, 0);
  }

  // ---- softmax over d (32 per head) fully in registers; head h = frags {2h, 2h+1}
  #pragma unroll
  for (int h = 0; h < 4; ++h) {
    #pragma unroll
    for (int j = 0; j < 2; ++j) {
      float m = -1e30f;
      #pragma unroll
      for (int r = 0; r < 4; ++r) m = fmaxf(m, fmaxf(acc[2 * h][j][r], acc[2 * h + 1][j][r]));
      m = fmaxf(m, __shfl_xor(m, 16));
      m = fmaxf(m, __shfl_xor(m, 32));
      float e0[4], e1[4], s = 0.f;
      #pragma unroll
      for (int r = 0; r < 4; ++r) {
        e0[r] = __expf(acc[2 * h][j][r] - m);
        e1[r] = __expf(acc[2 * h + 1][j][r] - m);
        s += e0[r] + e1[r];
      }
      s += __shfl_xor(s, 16);
      s += __shfl_xor(s, 32);
      const float inv = 1.f / s;
      #pragma unroll
      for (int r = 0; r < 4; ++r) {
        acc[2 * h][j][r] = e0[r] * inv;
        acc[2 * h + 1][j][r] = e1[r] * inv;
      }
    }
  }
  // ---- pack q_sm to bf16 pairs: pk[i][j] = {(r0,r1),(r2,r3)}
  unsigned int pk[8][2][2];
  #pragma unroll
  for (int i = 0; i < 8; ++i)
    #pragma unroll
    for (int j = 0; j < 2; ++j) {
      pk[i][j][0] = (unsigned int)f2bf(acc[i][j][0]) | ((unsigned int)f2bf(acc[i][j][1]) << 16);
      pk[i][j][1] = (unsigned int)f2bf(acc[i][j][2]) | ((unsigned int)f2bf(acc[i][j][3]) << 16);
    }

  // ---- GEMM2: out = M @ q_sm; B-frags via in-wave shuffles
  // dest lane (lr,lg), ks, j needs q_sm[d = ks*32+8lg+t][n=wn+16j+lr]:
  //   reg i_src = 2ks + (lg>>1); grp0 (t0..3) from lane lr+16*((2lg)&3), grp1 from +16.
  const int src0 = lr + ((lg & 1) ? 32 : 0);
  const int src1 = src0 + 16;
  const bool hi = (lg & 2) != 0;
  f32x4 acc2[8][2];
  #pragma unroll
  for (int i = 0; i < 8; ++i) { acc2[i][0] = 0.f; acc2[i][1] = 0.f; }
  const unsigned short* Mf = Mbf + (size_t)fr * 16384;
  #pragma unroll
  for (int ks = 0; ks < 4; ++ks) {
    const int k0 = ks * 32 + lg * 8;
    short8 a2[8];
    #pragma unroll
    for (int i2 = 0; i2 < 8; ++i2) a2[i2] = *(const short8*)&Mf[(16 * i2 + lr) * 128 + k0];
    short8 b[2];
    #pragma unroll
    for (int j = 0; j < 2; ++j) {
      const unsigned int s0 = hi ? pk[2 * ks + 1][j][0] : pk[2 * ks][j][0];
      const unsigned int s1 = hi ? pk[2 * ks + 1][j][1] : pk[2 * ks][j][1];
      union { int u[4]; short8 s8; } t;
      t.u[0] = __shfl((int)s0, src0);
      t.u[1] = __shfl((int)s1, src0);
      t.u[2] = __shfl((int)s0, src1);
      t.u[3] = __shfl((int)s1, src1);
      b[j] = t.s8;
    }
    #pragma unroll
    for (int i2 = 0; i2 < 8; ++i2)
      #pragma unroll
      for (int j = 0; j < 2; ++j)
        acc2[i2][j] = __builtin_amdgcn_mfma_f32_16x16x32_bf16(a2[i2], b[j], acc2[i2][j], 0, 0, 0);
  }

  // ---- direct stores: 16 lanes x 4B = 64B chunks, + bout
  float* ofr = out + ((size_t)bb * 2048 + ff) * 4096;   // + o*65536 + n
  #pragma unroll
  for (int i2 = 0; i2 < 8; ++i2) {
    const int o0 = 16 * i2 + 4 * lg;
    const float4 bo = *(const float4*)&bout[o0];
    #pragma unroll
    for (int j = 0; j < 2; ++j) {
      const int n = ntile * 128 + wn + 16 * j + lr;
      ofr[(size_t)(o0 + 0) * 65536 + n] = acc2[i2][j][0] + bo.x;
      ofr[(size_t)(o0 + 1) * 65536 + n] = acc2[i2][j][1] + bo.y;
      ofr[(size_t)(o0 + 2) * 65536 + n] = acc2[i2][j][2] + bo.z;
      ofr[(size_t)(o0 + 3) * 65536 + n] = acc2[i2][j][3] + bo.w;
    }
  }
}

extern "C" void kernel_launch(void* const* d_in, const int* in_sizes, int n_in,
                              void* d_out, int out_size, void* d_ws, size_t ws_size,
                              hipStream_t stream) {
  const float* x    = (const float*)d_in[0];
  const float* Wqkv = (const float*)d_in[1];
  const float* Wout = (const float*)d_in[2];
  const float* bout = (const float*)d_in[3];
  float* out = (float*)d_out;

  char* ws = (char*)d_ws;
  // ctxp f32 [512][4][32][32] | sexp f32 [512][128] | Mbf bf16 [32][128][128] | Wbf bf16 [384][128]
  float* ctxp = (float*)ws;                                  // 8,388,608 B
  float* sexp = (float*)(ws + 8388608u);                     //   262,144 B
  unsigned short* Mbf = (unsigned short*)(ws + 8650752u);    // 1,048,576 B
  unsigned short* Wbf = (unsigned short*)(ws + 9699328u);    //    98,304 B
  // total 9,797,632 B — all buffers fully written, no memset needed

  k_wconv<<<dim3(48), 256, 0, stream>>>(Wqkv, Wbf);
  k_ctxp<<<dim3(16, 32), 512, 0, stream>>>(x, Wbf, ctxp, sexp);
  k_mbuild<<<dim3(4, 32), 256, 0, stream>>>(Wout, ctxp, sexp, Mbf);
  k_fout<<<dim3(32, 32), 256, 0, stream>>>(x, Wbf, Mbf, bout, out);
}

// Round 7
// 219.250 us; speedup vs baseline: 1.1062x; 1.1062x over previous
//
#include <hip/hip_runtime.h>

// SpatialLinearAttention on MI355X — round 6 (resubmit; R6 bench was an infra timeout).
// n-major bf16 x (xb) materialized once; all GEMM staging becomes contiguous uint4
// copies. Fixes R5's scratch-spill (95MB phantom writes) and the 256KB-strided f32
// column gathers that capped HBM at ~2TB/s.
// k_prep  (x -> xb bf16 [fr][n][c] via LDS transpose; + Wqkv->bf16 in 4 tail blocks)
// k_ctxp  (k,v GEMM from xb + exp + reg-accumulated ctx/sumexp partials)
// k_mbuild(reduce 16 partials/frame -> M = Wout.blockdiag(ctx^T)*SCALE/n/sumexp, bf16)
// k_fout  (q GEMM from xb + in-reg softmax + in-reg shuffle B-frags + M@q_sm + bout)

constexpr float kSCALE = 0.17677669529663687f; // 32^-0.5

typedef __attribute__((ext_vector_type(8))) short short8;   // 8 bf16 (4 VGPRs)
typedef __attribute__((ext_vector_type(4))) float f32x4;    // MFMA acc

__device__ __forceinline__ float bfu2f(unsigned int u) {
  union { unsigned int i; float f; } c; c.i = u << 16; return c.f;
}
__device__ __forceinline__ unsigned short f2bf(float f) {
  union { float f; unsigned int i; } c; c.f = f;
  unsigned int r = c.i + 0x7fffu + ((c.i >> 16) & 1u);  // RNE
  return (unsigned short)(r >> 16);
}

// ---------------------------------------------------------------- K0: prep
// blocks 0..1023: transpose one [128c][128n] tile of x -> xb bf16 [fr][n][c]
// blocks 1024..1027: Wqkv f32 -> bf16
__global__ __launch_bounds__(256) void k_prep(const float* __restrict__ x,
                                              unsigned short* __restrict__ xb,
                                              const float* __restrict__ Wqkv,
                                              unsigned short* __restrict__ Wbf) {
  const int bid = blockIdx.x, tid = threadIdx.x;
  if (bid >= 1024) {   // ---- wconv tail: 4 blocks x 12288 elems
    const int base = (bid - 1024) * 12288 + tid * 4;
    #pragma unroll
    for (int p = 0; p < 12; ++p) {
      const int i = base + p * 1024;
      const float4 v = *(const float4*)&Wqkv[i];
      union { unsigned short u[4]; uint2 q; } t;
      t.u[0] = f2bf(v.x); t.u[1] = f2bf(v.y); t.u[2] = f2bf(v.z); t.u[3] = f2bf(v.w);
      *(uint2*)&Wbf[i] = t.q;
    }
    return;
  }
  __shared__ unsigned short Xt[128 * 130];   // [n][c], stride 130 (bank-spread)
  const int fr = bid >> 5, nb = (bid & 31) * 128;
  const int bb = fr >> 4, ff = fr & 15;
  const float* xfr = x + ((size_t)bb * 2048 + ff) * 4096;   // [c][n], c-stride 65536 f32
  // ---- read f32 float4 along n (512B segments), convert, scatter rows into LDS
  {
    const int nl4 = (tid & 31) * 4, c0 = tid >> 5;
    #pragma unroll
    for (int p = 0; p < 16; ++p) {
      const int c = c0 + p * 8;
      const float4 v = *(const float4*)&xfr[(size_t)c * 65536 + nb + nl4];
      Xt[(nl4 + 0) * 130 + c] = f2bf(v.x);
      Xt[(nl4 + 1) * 130 + c] = f2bf(v.y);
      Xt[(nl4 + 2) * 130 + c] = f2bf(v.z);
      Xt[(nl4 + 3) * 130 + c] = f2bf(v.w);
    }
  }
  __syncthreads();
  // ---- stream out: per n-row 256B contiguous; 4 rows/instr -> 1KB segments
  {
    const int c8 = (tid & 15) * 8;
    unsigned short* ob = xb + ((size_t)fr * 4096 + nb) * 128;
    #pragma unroll
    for (int p = 0; p < 8; ++p) {
      const int n = (tid >> 4) + p * 16;
      union { unsigned int u[4]; uint4 q; } t;
      #pragma unroll
      for (int j = 0; j < 4; ++j) t.u[j] = *(const unsigned int*)&Xt[n * 130 + c8 + 2 * j];
      *(uint4*)&ob[(size_t)n * 128 + c8] = t.q;
    }
  }
}

// ---------------------------------------------------------------- K1: ctx partials
// grid (16 ntiles of 256 n, 32 frames), 512 thr (8 waves; wave GEMM tile 64o x 32n).
// 4 subtiles of 64 n; ctx + sumexp accumulate in registers across subtiles.
__global__ __launch_bounds__(512, 4) void k_ctxp(const unsigned short* __restrict__ xb,
                                                 const unsigned short* __restrict__ Wbf,
                                                 float* __restrict__ ctxp,
                                                 float* __restrict__ sexp) {
  __shared__ __align__(16) unsigned short R0[2][64 * 128];  // x subtile [n][c^], dbuf
  __shared__ __align__(16) unsigned short EK[128 * 64];     // exp(k) [d][n^]
  __shared__ __align__(16) unsigned short VV[128 * 64];     // v      [e][n^]
  const int nt = blockIdx.x, fr = blockIdx.y;
  const int tid = threadIdx.x;
  const unsigned short* xrow = xb + ((size_t)fr * 4096 + nt * 256) * 128;

  const int l = tid & 63, w = tid >> 6;
  const int wo = (w >> 1) * 64, wn = (w & 1) * 32;          // W row = 128 + wo + ...
  const int lr = l & 15, lg = l >> 4;
  const int sc8 = (tid & 15) * 8, sn0 = tid >> 4;           // stage mapping (2 uint4/thr)

  f32x4 c2[2][2];                                           // ctx accum (waves 0-3)
  c2[0][0] = 0.f; c2[0][1] = 0.f; c2[1][0] = 0.f; c2[1][1] = 0.f;
  float se = 0.f;                                           // sumexp accum (waves 4-7)

  uint4 q0 = *(const uint4*)&xrow[(size_t)sn0 * 128 + sc8];
  uint4 q1 = *(const uint4*)&xrow[(size_t)(sn0 + 32) * 128 + sc8];

  #pragma unroll
  for (int sub = 0; sub < 4; ++sub) {
    unsigned short* Rb = R0[sub & 1];
    *(uint4*)&Rb[sn0 * 128 + (sc8 ^ ((sn0 & 7) << 3))] = q0;
    *(uint4*)&Rb[(sn0 + 32) * 128 + (sc8 ^ (((sn0 + 32) & 7) << 3))] = q1;
    __syncthreads();   // A: stage visible; prev-iter EK/VV readers done
    if (sub < 3) {     // prefetch next subtile (in flight during GEMM)
      q0 = *(const uint4*)&xrow[(size_t)((sub + 1) * 64 + sn0) * 128 + sc8];
      q1 = *(const uint4*)&xrow[(size_t)((sub + 1) * 64 + sn0 + 32) * 128 + sc8];
    }
    // GEMM k,v: 256 x 64 tile
    f32x4 acc[4][2];
    #pragma unroll
    for (int i = 0; i < 4; ++i) { acc[i][0] = 0.f; acc[i][1] = 0.f; }
    #pragma unroll
    for (int ks = 0; ks < 4; ++ks) {
      const int k0 = ks * 32 + lg * 8;
      short8 a[4], b[2];
      #pragma unroll
      for (int i = 0; i < 4; ++i)
        a[i] = *(const short8*)&Wbf[(size_t)(128 + wo + 16 * i + lr) * 128 + k0];
      #pragma unroll
      for (int j = 0; j < 2; ++j) {
        const int n = wn + 16 * j + lr;
        b[j] = *(const short8*)&Rb[n * 128 + (k0 ^ ((n & 7) << 3))];
      }
      #pragma unroll
      for (int i = 0; i < 4; ++i)
        #pragma unroll
        for (int j = 0; j < 2; ++j)
          acc[i][j] = __builtin_amdgcn_mfma_f32_16x16x32_bf16(a[i], b[j], acc[i][j], 0, 0, 0);
    }
    // k -> exp -> EK ; v -> VV
    if (wo < 128) {
      #pragma unroll
      for (int i = 0; i < 4; ++i)
        #pragma unroll
        for (int j = 0; j < 2; ++j) {
          const int n = wn + 16 * j + lr;
          #pragma unroll
          for (int r = 0; r < 4; ++r) {
            const int dd = wo + 16 * i + 4 * lg + r;
            EK[dd * 64 + (n ^ ((dd & 7) << 3))] = f2bf(__expf(acc[i][j][r]));
          }
        }
    } else {
      #pragma unroll
      for (int i = 0; i < 4; ++i)
        #pragma unroll
        for (int j = 0; j < 2; ++j) {
          const int n = wn + 16 * j + lr;
          #pragma unroll
          for (int r = 0; r < 4; ++r) {
            const int e = wo - 128 + 16 * i + 4 * lg + r;
            VV[e * 64 + (n ^ ((e & 7) << 3))] = f2bf(acc[i][j][r]);
          }
        }
    }
    __syncthreads();   // B: EK/VV visible; R0[sub&1] GEMM reads done
    if (w < 4) {
      const int h = w;
      #pragma unroll
      for (int ks2 = 0; ks2 < 2; ++ks2) {
        const int k0 = ks2 * 32 + lg * 8;
        short8 a2[2], b2[2];
        #pragma unroll
        for (int i2 = 0; i2 < 2; ++i2) {
          const int row = h * 32 + 16 * i2 + lr;
          a2[i2] = *(const short8*)&EK[row * 64 + (k0 ^ ((row & 7) << 3))];
          b2[i2] = *(const short8*)&VV[row * 64 + (k0 ^ ((row & 7) << 3))];
        }
        #pragma unroll
        for (int i2 = 0; i2 < 2; ++i2)
          #pragma unroll
          for (int j2 = 0; j2 < 2; ++j2)
            c2[i2][j2] = __builtin_amdgcn_mfma_f32_16x16x32_bf16(a2[i2], b2[j2], c2[i2][j2], 0, 0, 0);
      }
    } else {
      const int h = w - 4;
      const int rl = l & 31, half = l >> 5;
      const int row = h * 32 + rl;
      #pragma unroll
      for (int m = 0; m < 4; ++m) {
        const int ng = (half * 32 + m * 8) ^ ((row & 7) << 3);
        const uint4 u = *(const uint4*)&EK[row * 64 + ng];
        se += bfu2f(u.x & 0xffffu) + bfu2f(u.x >> 16) + bfu2f(u.y & 0xffffu) + bfu2f(u.y >> 16)
            + bfu2f(u.z & 0xffffu) + bfu2f(u.z >> 16) + bfu2f(u.w & 0xffffu) + bfu2f(u.w >> 16);
      }
    }
  }
  // epilogue: store reg-accumulated partials
  const int bp = fr * 16 + nt;
  if (w < 4) {
    float* cp = ctxp + ((size_t)bp * 4 + w) * 1024;
    #pragma unroll
    for (int i2 = 0; i2 < 2; ++i2)
      #pragma unroll
      for (int j2 = 0; j2 < 2; ++j2)
        #pragma unroll
        for (int r = 0; r < 4; ++r)
          cp[(16 * i2 + 4 * lg + r) * 32 + 16 * j2 + lr] = c2[i2][j2][r];
  } else {
    const int h = w - 4;
    const int rl = l & 31, half = l >> 5;
    se += __shfl_xor(se, 32);
    if (half == 0) sexp[(size_t)bp * 128 + h * 32 + rl] = se;
  }
}

// -------------------------------------------- K2: reduce partials + build M (bf16)
// grid (4 heads, 32 frames), 256 thr.
__global__ __launch_bounds__(256) void k_mbuild(const float* __restrict__ Wout,
                                                const float* __restrict__ ctxp,
                                                const float* __restrict__ sexp,
                                                unsigned short* __restrict__ Mbf) {
  __shared__ float Wo[128][33];   // Wout[o][h*32+e]
  __shared__ float cn[32][36];    // normalized ctx [d][e]
  __shared__ float ses[32];
  const int h = blockIdx.x, fr = blockIdx.y, tid = threadIdx.x;

  float4 c4 = make_float4(0.f, 0.f, 0.f, 0.f);
  {
    const float* base = ctxp + ((size_t)(fr * 16) * 4 + h) * 1024 + tid * 4;
    #pragma unroll
    for (int p = 0; p < 16; ++p) {
      const float4 v = *(const float4*)&base[(size_t)p * 4096];
      c4.x += v.x; c4.y += v.y; c4.z += v.z; c4.w += v.w;
    }
  }
  if (tid < 32) {
    float s = 0.f;
    const float* sb = sexp + (size_t)(fr * 16) * 128 + h * 32 + tid;
    #pragma unroll
    for (int p = 0; p < 16; ++p) s += sb[(size_t)p * 128];
    ses[tid] = s;
  }
  {
    const int o = tid >> 1, e0 = (tid & 1) * 16;
    #pragma unroll
    for (int q = 0; q < 4; ++q) {
      const float4 v = *(const float4*)&Wout[o * 128 + h * 32 + e0 + 4 * q];
      Wo[o][e0 + 4 * q] = v.x; Wo[o][e0 + 4 * q + 1] = v.y;
      Wo[o][e0 + 4 * q + 2] = v.z; Wo[o][e0 + 4 * q + 3] = v.w;
    }
  }
  __syncthreads();
  {
    const int dd = tid >> 3, e0 = (tid & 7) * 4;
    const float sc = kSCALE / (4096.f * ses[dd]);
    cn[dd][e0] = c4.x * sc; cn[dd][e0 + 1] = c4.y * sc;
    cn[dd][e0 + 2] = c4.z * sc; cn[dd][e0 + 3] = c4.w * sc;
  }
  __syncthreads();
  {
    const int o = tid >> 1, dbase = (tid & 1) * 16;
    union { unsigned short u[16]; uint4 q[2]; } t;
    #pragma unroll
    for (int dq = 0; dq < 16; ++dq) {
      const int dc = dbase + dq;
      float s = 0.f;
      #pragma unroll
      for (int e = 0; e < 32; ++e) s = fmaf(Wo[o][e], cn[dc][e], s);
      t.u[dq] = f2bf(s);
    }
    unsigned short* mb = Mbf + (size_t)fr * 16384 + o * 128 + h * 32 + dbase;
    *(uint4*)&mb[0] = t.q[0];
    *(uint4*)&mb[8] = t.q[1];
  }
}

// ---------------------------------------------------------------- K3: fused output
// grid (32 ntiles, 32 frames), 256 thr (4 waves; wave tile 128o x 32n).
// q GEMM (from xb) -> in-reg softmax -> shuffle B-frags -> M @ q_sm -> + bout -> stores.
__global__ __launch_bounds__(256, 3) void k_fout(const unsigned short* __restrict__ xb,
                                                 const unsigned short* __restrict__ Wbf,
                                                 const unsigned short* __restrict__ Mbf,
                                                 const float* __restrict__ bout,
                                                 float* __restrict__ out) {
  __shared__ __align__(16) unsigned short R0[128 * 128];   // x tile [n][c^]
  const int ntile = blockIdx.x, fr = blockIdx.y;
  const int bb = fr >> 4, ff = fr & 15;
  const int tid = threadIdx.x;

  // ---- stage xb tile: contiguous uint4 copies, swizzled LDS
  {
    const int c8 = (tid & 15) * 8;
    const unsigned short* xr = xb + ((size_t)fr * 4096 + ntile * 128) * 128;
    #pragma unroll
    for (int p = 0; p < 8; ++p) {
      const int n = (tid >> 4) + p * 16;
      const uint4 qv = *(const uint4*)&xr[(size_t)n * 128 + c8];
      *(uint4*)&R0[n * 128 + (c8 ^ ((n & 7) << 3))] = qv;
    }
  }
  __syncthreads();

  const int l = tid & 63, w = tid >> 6;
  const int wn = w * 32;
  const int lr = l & 15, lg = l >> 4;

  // ---- GEMM1: q = Wq @ x, wave tile 128 x 32
  f32x4 acc[8][2];
  #pragma unroll
  for (int i = 0; i < 8; ++i) { acc[i][0] = 0.f; acc[i][1] = 0.f; }
  #pragma unroll
  for (int ks = 0; ks < 4; ++ks) {
    const int k0 = ks * 32 + lg * 8;
    short8 a[8], b[2];
    #pragma unroll
    for (int i = 0; i < 8; ++i) a[i] = *(const short8*)&Wbf[(size_t)(16 * i + lr) * 128 + k0];
    #pragma unroll
    for (int j = 0; j < 2; ++j) {
      const int n = wn + 16 * j + lr;
      b[j] = *(const short8*)&R0[n * 128 + (k0 ^ ((n & 7) << 3))];
    }
    #pragma unroll
    for (int i = 0; i < 8; ++i)
      #pragma unroll
      for (int j = 0; j < 2; ++j)
        acc[i][j] = __builtin_amdgcn_mfma_f32_16x16x32_bf16(a[i], b[j], acc[i][j], 0, 0, 0);
  }

  // ---- softmax over d (32 per head) fully in registers; head h = frags {2h, 2h+1}
  #pragma unroll
  for (int h = 0; h < 4; ++h) {
    #pragma unroll
    for (int j = 0; j < 2; ++j) {
      float m = -1e30f;
      #pragma unroll
      for (int r = 0; r < 4; ++r) m = fmaxf(m, fmaxf(acc[2 * h][j][r], acc[2 * h + 1][j][r]));
      m = fmaxf(m, __shfl_xor(m, 16));
      m = fmaxf(m, __shfl_xor(m, 32));
      float e0[4], e1[4], s = 0.f;
      #pragma unroll
      for (int r = 0; r < 4; ++r) {
        e0[r] = __expf(acc[2 * h][j][r] - m);
        e1[r] = __expf(acc[2 * h + 1][j][r] - m);
        s += e0[r] + e1[r];
      }
      s += __shfl_xor(s, 16);
      s += __shfl_xor(s, 32);
      const float inv = 1.f / s;
      #pragma unroll
      for (int r = 0; r < 4; ++r) {
        acc[2 * h][j][r] = e0[r] * inv;
        acc[2 * h + 1][j][r] = e1[r] * inv;
      }
    }
  }
  // ---- pack q_sm to bf16 pairs: pk[i][j] = {(r0,r1),(r2,r3)}
  unsigned int pk[8][2][2];
  #pragma unroll
  for (int i = 0; i < 8; ++i)
    #pragma unroll
    for (int j = 0; j < 2; ++j) {
      pk[i][j][0] = (unsigned int)f2bf(acc[i][j][0]) | ((unsigned int)f2bf(acc[i][j][1]) << 16);
      pk[i][j][1] = (unsigned int)f2bf(acc[i][j][2]) | ((unsigned int)f2bf(acc[i][j][3]) << 16);
    }

  // ---- GEMM2: out = M @ q_sm; B-frags via in-wave shuffles
  const int src0 = lr + ((lg & 1) ? 32 : 0);
  const int src1 = src0 + 16;
  const bool hi = (lg & 2) != 0;
  f32x4 acc2[8][2];
  #pragma unroll
  for (int i = 0; i < 8; ++i) { acc2[i][0] = 0.f; acc2[i][1] = 0.f; }
  const unsigned short* Mf = Mbf + (size_t)fr * 16384;
  #pragma unroll
  for (int ks = 0; ks < 4; ++ks) {
    const int k0 = ks * 32 + lg * 8;
    short8 a2[8];
    #pragma unroll
    for (int i2 = 0; i2 < 8; ++i2) a2[i2] = *(const short8*)&Mf[(16 * i2 + lr) * 128 + k0];
    short8 b[2];
    #pragma unroll
    for (int j = 0; j < 2; ++j) {
      const unsigned int s0 = hi ? pk[2 * ks + 1][j][0] : pk[2 * ks][j][0];
      const unsigned int s1 = hi ? pk[2 * ks + 1][j][1] : pk[2 * ks][j][1];
      union { int u[4]; short8 s8; } t;
      t.u[0] = __shfl((int)s0, src0);
      t.u[1] = __shfl((int)s1, src0);
      t.u[2] = __shfl((int)s0, src1);
      t.u[3] = __shfl((int)s1, src1);
      b[j] = t.s8;
    }
    #pragma unroll
    for (int i2 = 0; i2 < 8; ++i2)
      #pragma unroll
      for (int j = 0; j < 2; ++j)
        acc2[i2][j] = __builtin_amdgcn_mfma_f32_16x16x32_bf16(a2[i2], b[j], acc2[i2][j], 0, 0, 0);
  }

  // ---- direct stores: 16 lanes x 4B = 64B chunks, + bout
  float* ofr = out + ((size_t)bb * 2048 + ff) * 4096;   // + o*65536 + n
  #pragma unroll
  for (int i2 = 0; i2 < 8; ++i2) {
    const int o0 = 16 * i2 + 4 * lg;
    const float4 bo = *(const float4*)&bout[o0];
    #pragma unroll
    for (int j = 0; j < 2; ++j) {
      const int n = ntile * 128 + wn + 16 * j + lr;
      ofr[(size_t)(o0 + 0) * 65536 + n] = acc2[i2][j][0] + bo.x;
      ofr[(size_t)(o0 + 1) * 65536 + n] = acc2[i2][j][1] + bo.y;
      ofr[(size_t)(o0 + 2) * 65536 + n] = acc2[i2][j][2] + bo.z;
      ofr[(size_t)(o0 + 3) * 65536 + n] = acc2[i2][j][3] + bo.w;
    }
  }
}

extern "C" void kernel_launch(void* const* d_in, const int* in_sizes, int n_in,
                              void* d_out, int out_size, void* d_ws, size_t ws_size,
                              hipStream_t stream) {
  const float* x    = (const float*)d_in[0];
  const float* Wqkv = (const float*)d_in[1];
  const float* Wout = (const float*)d_in[2];
  const float* bout = (const float*)d_in[3];
  float* out = (float*)d_out;

  char* ws = (char*)d_ws;
  // xb bf16 [32][4096][128] | ctxp f32 [512][4][32][32] | sexp f32 [512][128]
  // | Mbf bf16 [32][128][128] | Wbf bf16 [384][128]
  unsigned short* xb  = (unsigned short*)ws;                  // 33,554,432 B
  float* ctxp = (float*)(ws + 33554432u);                     //  8,388,608 B
  float* sexp = (float*)(ws + 41943040u);                     //    262,144 B
  unsigned short* Mbf = (unsigned short*)(ws + 42205184u);    //  1,048,576 B
  unsigned short* Wbf = (unsigned short*)(ws + 43253760u);    //     98,304 B
  // total 43,352,064 B — all buffers fully written, no memset needed

  k_prep<<<dim3(1028), 256, 0, stream>>>(x, xb, Wqkv, Wbf);
  k_ctxp<<<dim3(16, 32), 512, 0, stream>>>(xb, Wbf, ctxp, sexp);
  k_mbuild<<<dim3(4, 32), 256, 0, stream>>>(Wout, ctxp, sexp, Mbf);
  k_fout<<<dim3(32, 32), 256, 0, stream>>>(xb, Wbf, Mbf, bout, out);
}